// Round 9
// baseline (73.034 us; speedup 1.0000x reference)
//
#include <hip/hip_runtime.h>
#include <hip/hip_cooperative_groups.h>
#include <math.h>

namespace cg = cooperative_groups;

// Problem dims (fixed by reference setup_inputs)
#define B 8
#define NPTS 20000
#define M 1024
#define H 1024
#define BN_EPS 1e-5f

#define MC 16                    // m per 256-thread group
#define NPAIRS (NPTS / 2)        // 10000
#define HALFP (NPAIRS / 2)       // 5000 pairs per half-group

typedef float f2 __attribute__((ext_vector_type(2)));

struct Params {
    const float *x, *basis;
    const float *g1, *bb1, *rm1, *rv1;
    const float *w1, *b1;
    const float *g2, *bb2, *rm2, *rv2;
    const float *w2, *b2;
    float *out;
    float *fsg;    // [B][M] bn1 features
};

// ---------------------------------------------------------------------------
// Phase A (per block of 1024 thr): two units u=tid>>9; unit vbid=bid*2+u ->
// (b=vbid>>6, mc=vbid&63). Both units share b (same x stream). Within a unit,
// half h=(tid>>8)&1 covers pairs [h*5000,(h+1)*5000): 20 iters, depth-1
// prefetched, tail clamped (duplicate pairs harmless under min).
// 16 m per thread in registers; wave shuffle-reduce; 8-wave LDS combine;
// fused sqrt+bn1 -> fsg. Block 0 seeds out[b]=b2.
// ---------------------------------------------------------------------------
__device__ __forceinline__ void phaseA(const Params& p, int bid, int tid) {
    __shared__ float smin[2][8][MC];
    const int lane = tid & 63;
    const int u = tid >> 9;            // unit 0..1
    const int ut = tid & 511;          // thread in unit
    const int h = ut >> 8;             // half 0..1
    const int st = ut & 255;           // thread in half-group
    const int wu = (tid >> 6) & 7;     // wave in unit

    const int vbid = bid * 2 + u;      // 0..511
    const int b = vbid >> 6;           // 0..7
    const int mc = vbid & 63;          // 0..63
    const int m0 = mc * MC;
    const float* xb = p.x + (size_t)b * 3 * NPTS;

    float nbx[MC], nby[MC], nbz[MC];
#pragma unroll
    for (int i = 0; i < MC; ++i) {
        int m = m0 + i;
        nbx[i] = -2.0f * p.basis[m * 3 + 0];
        nby[i] = -2.0f * p.basis[m * 3 + 1];
        nbz[i] = -2.0f * p.basis[m * 3 + 2];
    }
    float acc[MC];
#pragma unroll
    for (int i = 0; i < MC; ++i) acc[i] = INFINITY;

    const int p0 = h * HALFP;
    const int plast = p0 + HALFP - 1;

    // prologue: load iter 0
    int pi = p0 + st;
    f2 X = *reinterpret_cast<const f2*>(xb + 2 * pi);
    f2 Y = *reinterpret_cast<const f2*>(xb + NPTS + 2 * pi);
    f2 Z = *reinterpret_cast<const f2*>(xb + 2 * NPTS + 2 * pi);

    for (int c = 0; c < 20; ++c) {
        f2 Xc = X, Yc = Y, Zc = Z;
        if (c < 19) {                          // depth-1 prefetch (clamped tail)
            int pn = p0 + (c + 1) * 256 + st;
            pn = pn > plast ? plast : pn;
            X = *reinterpret_cast<const f2*>(xb + 2 * pn);
            Y = *reinterpret_cast<const f2*>(xb + NPTS + 2 * pn);
            Z = *reinterpret_cast<const f2*>(xb + 2 * NPTS + 2 * pn);
        }
        f2 W = Xc * Xc;
        W = __builtin_elementwise_fma(Yc, Yc, W);
        W = __builtin_elementwise_fma(Zc, Zc, W);
#pragma unroll
        for (int i = 0; i < MC; ++i) {
            f2 s = __builtin_elementwise_fma(Xc, (f2){nbx[i], nbx[i]}, W);
            s = __builtin_elementwise_fma(Yc, (f2){nby[i], nby[i]}, s);
            s = __builtin_elementwise_fma(Zc, (f2){nbz[i], nbz[i]}, s);
            acc[i] = fminf(acc[i], fminf(s.x, s.y));
        }
    }

    // wave min-reduce
#pragma unroll
    for (int i = 0; i < MC; ++i) {
#pragma unroll
        for (int off = 32; off > 0; off >>= 1) {
            acc[i] = fminf(acc[i], __shfl_down(acc[i], off, 64));
        }
    }
    if (lane == 0) {
#pragma unroll
        for (int i = 0; i < MC; ++i) smin[u][wu][i] = acc[i];
    }
    __syncthreads();

    if (ut < MC) {
        int m = m0 + ut;
        float v = INFINITY;
#pragma unroll
        for (int q = 0; q < 8; ++q) v = fminf(v, smin[u][q][ut]);
        float bx = p.basis[m * 3 + 0];
        float by = p.basis[m * 3 + 1];
        float bz = p.basis[m * 3 + 2];
        v = fmaxf(v + bx * bx + by * by + bz * bz, 0.0f);  // + |b|^2, clip
        float f = sqrtf(v);
        float sc = p.g1[m] * rsqrtf(p.rv1[m] + BN_EPS);
        p.fsg[b * M + m] = (f - p.rm1[m]) * sc + p.bb1[m];
    }
    if (bid == 0 && tid < B) {
        p.out[tid] = p.b2[0];
    }
}

// ---------------------------------------------------------------------------
// Phase C (blocks 0..63, 1024 thr): wave w owns row i=bid*16+w; full-M dot
// for all 8 batches from fsg (L2-resident), shuffle-reduce, bn2 + w2-scale,
// 16-wave LDS combine, 8 atomicAdds into out.
// ---------------------------------------------------------------------------
__device__ __forceinline__ void phaseC(const Params& p, int bid, int tid) {
    __shared__ float cpart[16][B];
    const int lane = tid & 63;
    const int w = tid >> 6;             // 0..15
    const int i = bid * 16 + w;         // row 0..1023
    const float* wrow = p.w1 + (size_t)i * M;

    float hsum[B] = {0, 0, 0, 0, 0, 0, 0, 0};
#pragma unroll
    for (int seg = 0; seg < 4; ++seg) {
        int m0 = seg * 256 + lane * 4;
        float4 wv4 = *reinterpret_cast<const float4*>(wrow + m0);
#pragma unroll
        for (int bb = 0; bb < B; ++bb) {
            float4 fv = *reinterpret_cast<const float4*>(&p.fsg[bb * M + m0]);
            hsum[bb] = fmaf(fv.x, wv4.x, hsum[bb]);
            hsum[bb] = fmaf(fv.y, wv4.y, hsum[bb]);
            hsum[bb] = fmaf(fv.z, wv4.z, hsum[bb]);
            hsum[bb] = fmaf(fv.w, wv4.w, hsum[bb]);
        }
    }
#pragma unroll
    for (int bb = 0; bb < B; ++bb) {
#pragma unroll
        for (int off = 32; off > 0; off >>= 1) {
            hsum[bb] += __shfl_down(hsum[bb], off, 64);
        }
    }
    if (lane == 0) {
        float b1i = p.b1[i];
        float sc2 = p.g2[i] * rsqrtf(p.rv2[i] + BN_EPS);
        float rm = p.rm2[i];
        float bt = p.bb2[i];
        float w2i = p.w2[i];
#pragma unroll
        for (int bb = 0; bb < B; ++bb) {
            float v = fmaxf(hsum[bb] + b1i, 0.0f);
            v = (v - rm) * sc2 + bt;
            cpart[w][bb] = v * w2i;
        }
    }
    __syncthreads();
    if (tid < B) {
        float s = 0.0f;
#pragma unroll
        for (int q = 0; q < 16; ++q) s += cpart[q][tid];
        atomicAdd(&p.out[tid], s);
    }
}

// ---------------------------------------------------------------------------
__global__ __launch_bounds__(1024) void fused_kernel(Params p) {
    phaseA(p, blockIdx.x, threadIdx.x);
    cg::this_grid().sync();
    if (blockIdx.x < H / 16) phaseC(p, blockIdx.x, threadIdx.x);
}

// fallback path (plain launches, stream-ordered) in case coop launch is
// rejected (round-7 lesson: rejection is silent at capture time otherwise)
__global__ __launch_bounds__(1024) void kA(Params p) { phaseA(p, blockIdx.x, threadIdx.x); }
__global__ __launch_bounds__(1024) void kC(Params p) { phaseC(p, blockIdx.x, threadIdx.x); }

// ---------------------------------------------------------------------------
extern "C" void kernel_launch(void* const* d_in, const int* in_sizes, int n_in,
                              void* d_out, int out_size, void* d_ws, size_t ws_size,
                              hipStream_t stream) {
    Params prm;
    prm.x     = (const float*)d_in[0];
    prm.basis = (const float*)d_in[1];
    prm.g1    = (const float*)d_in[2];
    prm.bb1   = (const float*)d_in[3];
    prm.rm1   = (const float*)d_in[4];
    prm.rv1   = (const float*)d_in[5];
    prm.w1    = (const float*)d_in[6];
    prm.b1    = (const float*)d_in[7];
    prm.g2    = (const float*)d_in[8];
    prm.bb2   = (const float*)d_in[9];
    prm.rm2   = (const float*)d_in[10];
    prm.rv2   = (const float*)d_in[11];
    prm.w2    = (const float*)d_in[12];
    prm.b2    = (const float*)d_in[13];
    prm.out   = (float*)d_out;
    prm.fsg   = (float*)d_ws;              // 8*1024 floats

    void* args[] = { &prm };
    hipError_t err = hipLaunchCooperativeKernel((const void*)fused_kernel,
                                                dim3(256), dim3(1024), args, 0, stream);
    if (err != hipSuccess) {
        kA<<<256, 1024, 0, stream>>>(prm);
        kC<<<H / 16, 1024, 0, stream>>>(prm);
    }
}